// Round 7
// baseline (227.942 us; speedup 1.0000x reference)
//
#include <hip/hip_runtime.h>
#include <math.h>

#define NU_F 0.0031830988618379067f
#define KTANH 2.885390082f   // 2*log2(e)

typedef _Float16 f16x8 __attribute__((ext_vector_type(8)));
typedef float    f32x4 __attribute__((ext_vector_type(4)));

// tanh from PRE-SCALED argument zs = 2*log2(e)*z:
// tanh(z) = 1 - 2/(exp2(zs)+1); 4 VALU (2 transcendental)
__device__ __forceinline__ float tanh_pre(float zs) {
    float e = __builtin_amdgcn_exp2f(zs);
    float r = __builtin_amdgcn_rcpf(e + 1.0f);
    return fmaf(-2.0f, r, 1.0f);
}

// pack two f32 -> f16x2 in one u32 (v_cvt_pkrtz_f32_f16), low16 = a
__device__ __forceinline__ unsigned pkf16(float a, float b) {
    auto v = __builtin_amdgcn_cvt_pkrtz(a, b);   // __fp16 ext_vector(2)
    return __builtin_bit_cast(unsigned, v);
}

// LDS-only barrier: order LDS ops across waves WITHOUT draining vmcnt.
__device__ __forceinline__ void lds_barrier() {
    asm volatile("s_waitcnt lgkmcnt(0)" ::: "memory");
    __builtin_amdgcn_s_barrier();
}

// ---------------------------------------------------------------------------
// Prep (gather-read, COALESCED-write) — unchanged from round 6.
// ---------------------------------------------------------------------------
__global__ void prep_wfrag(const float* __restrict__ Whid, _Float16* __restrict__ wcf)
{
    const int t    = blockIdx.x * 256 + threadIdx.x;   // 0 .. 14335
    const int lane = t & 63;
    const int fid  = t >> 6;          // (l*8 + nt)*4 + ks, 0..223
    const int ks = fid & 3;
    const int nt = (fid >> 2) & 7;
    const int l  = fid >> 5;
    const int q  = lane >> 4;
    const int nn = lane & 15;
    const int c  = ((nt >> 1) << 5) + nn * 2 + (nt & 1);
    const int k0 = ks * 32 + q * 8;
    const float* src = Whid + l * 16384 + k0 * 128 + c;
    f16x8 v;
    #pragma unroll
    for (int jj = 0; jj < 8; ++jj)
        v[jj] = (_Float16)src[jj * 128];
    *(f16x8*)(wcf + (size_t)t * 8) = v;
}

#define HR 68
#define MFMA(A, B, C) __builtin_amdgcn_mfma_f32_16x16x32_f16((A), (B), (C), 0, 0, 0)

// K-loop: 16 ds_read_b128 + 16 MFMA into acc[4][2] (deriv: 4 states; value:
// 4 m-tiles — identical shape, different H row meaning).
__device__ __forceinline__ void kloop(f32x4 (&acc)[4][2],
        const unsigned* __restrict__ Hc,
        const f16x8& cB0, const f16x8& cB1,
        const _Float16* __restrict__ pb0, const _Float16* __restrict__ pb1,
        int lm, int lq)
{
    #pragma unroll
    for (int s = 0; s < 4; ++s)
        #pragma unroll
        for (int j = 0; j < 2; ++j) acc[s][j] = (f32x4){0.f, 0.f, 0.f, 0.f};
    {   // ks = 0: B pair from cross-phase prefetch registers
        const int ro = lq * 4;
        const f16x8 ah0 = *(const f16x8*)&Hc[(0 * 16 + lm) * HR + ro];
        const f16x8 ah1 = *(const f16x8*)&Hc[(1 * 16 + lm) * HR + ro];
        const f16x8 ah2 = *(const f16x8*)&Hc[(2 * 16 + lm) * HR + ro];
        const f16x8 ah3 = *(const f16x8*)&Hc[(3 * 16 + lm) * HR + ro];
        acc[0][0] = MFMA(ah0, cB0, acc[0][0]);
        acc[1][0] = MFMA(ah1, cB0, acc[1][0]);
        acc[2][0] = MFMA(ah2, cB0, acc[2][0]);
        acc[3][0] = MFMA(ah3, cB0, acc[3][0]);
        acc[0][1] = MFMA(ah0, cB1, acc[0][1]);
        acc[1][1] = MFMA(ah1, cB1, acc[1][1]);
        acc[2][1] = MFMA(ah2, cB1, acc[2][1]);
        acc[3][1] = MFMA(ah3, cB1, acc[3][1]);
    }
    #pragma unroll
    for (int ks = 1; ks < 4; ++ks) {
        const int ro = ks * 16 + lq * 4;
        const f16x8 ah0 = *(const f16x8*)&Hc[(0 * 16 + lm) * HR + ro];
        const f16x8 ah1 = *(const f16x8*)&Hc[(1 * 16 + lm) * HR + ro];
        const f16x8 ah2 = *(const f16x8*)&Hc[(2 * 16 + lm) * HR + ro];
        const f16x8 ah3 = *(const f16x8*)&Hc[(3 * 16 + lm) * HR + ro];
        const f16x8 b0 = *(const f16x8*)(pb0 + ks * 512);
        const f16x8 b1 = *(const f16x8*)(pb1 + ks * 512);
        acc[0][0] = MFMA(ah0, b0, acc[0][0]);
        acc[1][0] = MFMA(ah1, b0, acc[1][0]);
        acc[2][0] = MFMA(ah2, b0, acc[2][0]);
        acc[3][0] = MFMA(ah3, b0, acc[3][0]);
        acc[0][1] = MFMA(ah0, b1, acc[0][1]);
        acc[1][1] = MFMA(ah1, b1, acc[1][1]);
        acc[2][1] = MFMA(ah2, b1, acc[2][1]);
        acc[3][1] = MFMA(ah3, b1, acc[3][1]);
    }
}

// Derivative-path jet epilogue: acc[state][j] -> H rows s*16+p.
__device__ __forceinline__ void epi_deriv(const f32x4 (&acc)[4][2],
        float bbs0, float bbs1, unsigned* __restrict__ Hn, int lq, int wc)
{
    #pragma unroll
    for (int r = 0; r < 4; ++r) {
        const int p = lq * 4 + r;
        float h[2][4];
        #pragma unroll
        for (int j = 0; j < 2; ++j) {
            const float zx  = acc[1][j][r];
            const float zt  = acc[2][j][r];
            const float zxx = acc[3][j][r];
            const float y = tanh_pre(fmaf(acc[0][j][r], KTANH, j ? bbs1 : bbs0));
            const float d = fmaf(-y, y, 1.f);
            const float m = d * zx;
            h[j][0] = y;
            h[j][1] = m;
            h[j][2] = d * zt;
            h[j][3] = fmaf(d, zxx, -2.f * (y * m) * zx);
        }
        #pragma unroll
        for (int s = 0; s < 4; ++s)
            Hn[(s * 16 + p) * HR + wc] = pkf16(h[0][s], h[1][s]);
    }
}

// Value-path epilogue: acc[mt][j] -> H rows mt*16+p.
__device__ __forceinline__ void epi_val(const f32x4 (&acc)[4][2],
        float bbs0, float bbs1, unsigned* __restrict__ Hn, int lq, int wc)
{
    #pragma unroll
    for (int mt = 0; mt < 4; ++mt) {
        #pragma unroll
        for (int r = 0; r < 4; ++r) {
            const int p = mt * 16 + lq * 4 + r;
            const float y0 = tanh_pre(fmaf(acc[mt][0][r], KTANH, bbs0));
            const float y1 = tanh_pre(fmaf(acc[mt][1][r], KTANH, bbs1));
            Hn[p * HR + wc] = pkf16(y0, y1);
        }
    }
}

// ---------------------------------------------------------------------------
// Fused kernel, 256 thr = 4 waves, DUAL-PROBLEM PING-PONG.
// Each block owns TWO independent 16-point (deriv) / 64-point (value)
// problems A and B. Phase structure per layer l:
//   phase1: A.kloop(l)  [MFMA]  || B.epi(l-1) [VALU]   -> lds_barrier
//   phase2: B.kloop(l)  [MFMA]  || prefetch B(l+1) || A.epi(l) -> lds_barrier
// Every barrier-to-barrier region has MFMA + independent VALU in the SAME
// wave -> deterministic pipe overlap instead of relying on occupancy.
// H_A, H_B single-buffered (17.4 KB each): A.kloop(l) reads H_A before the
// barrier behind which A.epi(l) overwrites it — safe. Both problems share
// W(l): cB regs + L1-hot in-loop reads -> half the B traffic per point.
// ---------------------------------------------------------------------------
__global__ __launch_bounds__(256, 4)
void pinn_fused(const float* __restrict__ xf,
                const float* __restrict__ x0,  const float* __restrict__ xbl,
                const float* __restrict__ xbr,
                const float* __restrict__ Win,  const float* __restrict__ bin,
                const float* __restrict__ bhid,
                const float* __restrict__ Wout, const float* __restrict__ bout,
                const _Float16* __restrict__ wcf,
                float* __restrict__ out)
{
    __shared__ unsigned Hh[2][64 * HR];   // [0]=H_A, [1]=H_B
    __shared__ float xpt[256];
    __shared__ float pbuf[512];
    __shared__ float dots[128];

    const int tid  = threadIdx.x;
    const int lane = tid & 63;
    const int wv   = tid >> 6;         // wave 0..3 -> N-tiles 2wv,2wv+1
    const int lm   = lane & 15;
    const int lq   = lane >> 4;
    const int blk  = blockIdx.x;
    const bool isv = (blk >= 4096);

    if (!isv) {
        if (tid < 64) xpt[tid] = xf[blk * 64 + tid];   // 32 points (A:0-15,B:16-31)
    } else {
        const int vb = blk - 4096;                     // 0..63
        const int vp = vb * 2 + (tid >> 7);            // A / B value sub-block
        const float* src = (vp < 64) ? (x0 + vp * 128)
                         : (vp < 96) ? (xbl + (vp - 64) * 128)
                                     : (xbr + (vp - 96) * 128);
        xpt[tid] = src[tid & 127];
    }

    // ---- prologue prefetch: layer-0 ks=0 B pair + bias ----
    const _Float16* pb0 = wcf + (wv * 2 + 0) * 2048 + lane * 8;
    const _Float16* pb1 = wcf + (wv * 2 + 1) * 2048 + lane * 8;
    const float* bptr = bhid + wv * 32 + lm * 2;
    f16x8 cB0 = *(const f16x8*)pb0;
    f16x8 cB1 = *(const f16x8*)pb1;
    float2 btc_cur = *(const float2*)bptr;
    float2 btc_prev;

    __syncthreads();   // xpt ready

    // ---- input layer: thread owns channel pair cp; fill H_A and H_B ----
    const int cp = tid & 63;
    {
        const float2 w01 = *(const float2*)&Win[cp * 2];
        const float2 w11 = *(const float2*)&Win[128 + cp * 2];
        const float2 bb  = *(const float2*)&bin[cp * 2];
        const float w01sx = w01.x * KTANH, w01sy = w01.y * KTANH;
        const float w11sx = w11.x * KTANH, w11sy = w11.y * KTANH;
        const float bbsx  = bb.x  * KTANH, bbsy  = bb.y  * KTANH;
        if (!isv) {
            #pragma unroll
            for (int g = 0; g < 2; ++g) {
                const int xo = g * 32;
                const int p0 = wv * 4;
                #pragma unroll
                for (int i = 0; i < 4; ++i) {
                    const int p = p0 + i;
                    const float x = xpt[xo + 2 * p], tt = xpt[xo + 2 * p + 1];
                    const float ya = tanh_pre(fmaf(x, w01sx, fmaf(tt, w11sx, bbsx)));
                    const float yb = tanh_pre(fmaf(x, w01sy, fmaf(tt, w11sy, bbsy)));
                    const float da = 1.f - ya * ya, db = 1.f - yb * yb;
                    unsigned* H = Hh[g];
                    H[(0 * 16 + p) * HR + cp] = pkf16(ya, yb);
                    H[(1 * 16 + p) * HR + cp] = pkf16(da * w01.x, db * w01.y);
                    H[(2 * 16 + p) * HR + cp] = pkf16(da * w11.x, db * w11.y);
                    H[(3 * 16 + p) * HR + cp] =
                        pkf16(-2.f * ya * da * w01.x * w01.x,
                              -2.f * yb * db * w01.y * w01.y);
                }
            }
        } else {
            #pragma unroll
            for (int g = 0; g < 2; ++g) {
                const int xo = g * 128;
                const int p0 = wv * 16;
                #pragma unroll
                for (int i = 0; i < 16; ++i) {
                    const int p = p0 + i;
                    const float x = xpt[xo + 2 * p], tt = xpt[xo + 2 * p + 1];
                    const float ya = tanh_pre(fmaf(x, w01sx, fmaf(tt, w11sx, bbsx)));
                    const float yb = tanh_pre(fmaf(x, w01sy, fmaf(tt, w11sy, bbsy)));
                    Hh[g][p * HR + cp] = pkf16(ya, yb);
                }
            }
        }
    }
    lds_barrier();

    const int wc = wv * 16 + lm;   // epilogue dword column (channel pair)

    f32x4 accA[4][2], accB[4][2];

    if (!isv) {
        // ================= derivative path (dual ping-pong) =================
        for (int l = 0; l < 7; ++l) {
            // ---- phase1: A.kloop(l) || B.epi(l-1) ----
            kloop(accA, Hh[0], cB0, cB1, pb0, pb1, lm, lq);
            if (l > 0)
                epi_deriv(accB, btc_prev.x * KTANH, btc_prev.y * KTANH,
                          Hh[1], lq, wc);
            lds_barrier();

            // ---- phase2: B.kloop(l) || prefetch(l+1) || A.epi(l) ----
            kloop(accB, Hh[1], cB0, cB1, pb0, pb1, lm, lq);
            btc_prev = btc_cur;
            pb0 += 16384; pb1 += 16384;
            if (l < 6) {
                cB0 = *(const f16x8*)pb0;
                cB1 = *(const f16x8*)pb1;
                btc_cur = *(const float2*)(bptr + 128);
                bptr += 128;
            }
            epi_deriv(accA, btc_prev.x * KTANH, btc_prev.y * KTANH,
                      Hh[0], lq, wc);
            lds_barrier();
        }
        // tail: B.epi(6)
        epi_deriv(accB, btc_prev.x * KTANH, btc_prev.y * KTANH, Hh[1], lq, wc);
        lds_barrier();
    } else {
        // ================= value-only path (dual ping-pong) =================
        for (int l = 0; l < 7; ++l) {
            kloop(accA, Hh[0], cB0, cB1, pb0, pb1, lm, lq);
            if (l > 0)
                epi_val(accB, btc_prev.x * KTANH, btc_prev.y * KTANH,
                        Hh[1], lq, wc);
            lds_barrier();

            kloop(accB, Hh[1], cB0, cB1, pb0, pb1, lm, lq);
            btc_prev = btc_cur;
            pb0 += 16384; pb1 += 16384;
            if (l < 6) {
                cB0 = *(const f16x8*)pb0;
                cB1 = *(const f16x8*)pb1;
                btc_cur = *(const float2*)(bptr + 128);
                bptr += 128;
            }
            epi_val(accA, btc_prev.x * KTANH, btc_prev.y * KTANH, Hh[0], lq, wc);
            lds_barrier();
        }
        epi_val(accB, btc_prev.x * KTANH, btc_prev.y * KTANH, Hh[1], lq, wc);
        lds_barrier();
    }

    // ---- output layer: both problems ----
    {
        const int st = lane;           // H row 0..63
        const int cb = wv * 16;        // 16 dwords = 32 channels per chunk
        float pA = 0.f, pB = 0.f;
        #pragma unroll
        for (int c8 = 0; c8 < 4; ++c8) {
            const f16x8 hA = *(const f16x8*)&Hh[0][st * HR + cb + c8 * 4];
            const f16x8 hB = *(const f16x8*)&Hh[1][st * HR + cb + c8 * 4];
            const float4 w1 = *(const float4*)&Wout[wv * 32 + c8 * 8];
            const float4 w2 = *(const float4*)&Wout[wv * 32 + c8 * 8 + 4];
            pA = fmaf((float)hA[0], w1.x, pA);
            pA = fmaf((float)hA[1], w1.y, pA);
            pA = fmaf((float)hA[2], w1.z, pA);
            pA = fmaf((float)hA[3], w1.w, pA);
            pA = fmaf((float)hA[4], w2.x, pA);
            pA = fmaf((float)hA[5], w2.y, pA);
            pA = fmaf((float)hA[6], w2.z, pA);
            pA = fmaf((float)hA[7], w2.w, pA);
            pB = fmaf((float)hB[0], w1.x, pB);
            pB = fmaf((float)hB[1], w1.y, pB);
            pB = fmaf((float)hB[2], w1.z, pB);
            pB = fmaf((float)hB[3], w1.w, pB);
            pB = fmaf((float)hB[4], w2.x, pB);
            pB = fmaf((float)hB[5], w2.y, pB);
            pB = fmaf((float)hB[6], w2.z, pB);
            pB = fmaf((float)hB[7], w2.w, pB);
        }
        pbuf[wv * 64 + st] = pA;
        pbuf[256 + wv * 64 + st] = pB;
    }
    lds_barrier();
    if (tid < 128) {
        const float* q = pbuf + (tid >> 6) * 256;
        const int t = tid & 63;
        dots[tid] = (q[t] + q[64 + t]) + (q[128 + t] + q[192 + t]);
    }
    lds_barrier();
    if (!isv) {
        if (tid < 16) {
            const float u = dots[tid] + bout[0];
            out[8192 + blk * 32 + tid] =
                dots[32 + tid] + u * dots[16 + tid] - NU_F * dots[48 + tid];
        } else if (tid >= 64 && tid < 80) {
            const int t = tid - 64;
            const float u = dots[64 + t] + bout[0];
            out[8192 + blk * 32 + 16 + t] =
                dots[96 + t] + u * dots[80 + t] - NU_F * dots[112 + t];
        }
    } else {
        const int vb = blk - 4096;
        if (tid < 128)
            out[vb * 128 + tid] = dots[tid] + bout[0];
    }
}

extern "C" void kernel_launch(void* const* d_in, const int* in_sizes, int n_in,
                              void* d_out, int out_size, void* d_ws, size_t ws_size,
                              hipStream_t stream) {
    (void)in_sizes; (void)n_in; (void)ws_size; (void)out_size;
    const float* xf   = (const float*)d_in[0];
    const float* x0   = (const float*)d_in[1];
    const float* xbl  = (const float*)d_in[2];
    const float* xbr  = (const float*)d_in[3];
    const float* Win  = (const float*)d_in[4];
    const float* bin  = (const float*)d_in[5];
    const float* Whid = (const float*)d_in[6];
    const float* bhid = (const float*)d_in[7];
    const float* Wout = (const float*)d_in[8];
    const float* bout = (const float*)d_in[9];
    float* out = (float*)d_out;

    _Float16* wcf = (_Float16*)d_ws;   // 7*128*128 f16 = 224 KiB

    hipLaunchKernelGGL(prep_wfrag, dim3(14336 / 256), dim3(256), 0, stream,
                       Whid, wcf);
    hipLaunchKernelGGL(pinn_fused, dim3(4096 + 64), dim3(256), 0, stream,
                       xf, x0, xbl, xbr, Win, bin, bhid, Wout, bout, wcf, out);
}